// Round 10
// baseline (157.002 us; speedup 1.0000x reference)
//
#include <hip/hip_runtime.h>
#include <stdint.h>

typedef short short8 __attribute__((ext_vector_type(8)));
typedef short short4_t __attribute__((ext_vector_type(4)));
typedef float f32x4 __attribute__((ext_vector_type(4)));

__device__ __forceinline__ float bf2f(unsigned short u) {
    union { unsigned int i; float f; } v; v.i = ((unsigned int)u) << 16; return v.f;
}
// round-half-up bf16 (max 0.5 ulp, 2 VALU ops)
__device__ __forceinline__ unsigned short f2bf(float f) {
    union { float f; unsigned int i; } v; v.f = f;
    return (unsigned short)((v.i + 0x8000u) >> 16);
}

// ---------------- kernel A: weight transpose (f32 -> bf16 hi, + lo f/g) ----
__global__ void k_wtrans(const float* __restrict__ Wf,
                         const float* __restrict__ Wg,
                         const float* __restrict__ Wh,
                         unsigned short* __restrict__ wTh,
                         unsigned short* __restrict__ wTl) {
    int col = blockIdx.x;   // 0..319
    int k = threadIdx.x;    // 0..255
    float v;
    if (col < 32) v = Wf[k * 32 + col];
    else if (col < 64) v = Wg[k * 32 + (col - 32)];
    else v = Wh[k * 256 + (col - 64)];
    unsigned short h = f2bf(v);
    wTh[col * 256 + k] = h;
    if (col < 64) wTl[col * 256 + k] = f2bf(v - bf2f(h));
}

// ---------------- kernel B: fused projections (grid 256) -------------------
// One block per 64-row tile; x read ONCE (fp32), converted to bf16 hi/lo in
// LDS; loops over 5 W column-blocks (cb 0..3 = h, cb 4 = f,g 3-term hi/lo).
// Outputs in FRAGMENT-LINEAR layouts (verified R9):
//   fK/gQ: tile=[b*256+row>>4], within: chunk=(ch>>3)*16+(row&15), elem=ch&7
//   hT:    [b*16+ch>>4][key>>5][chunk=((key&31)>>3)*16+(ch&15)][elem=key&7]
__global__ __launch_bounds__(256) void k_proj(
    const float* __restrict__ x,
    const unsigned short* __restrict__ wTh,
    const unsigned short* __restrict__ wTl,
    const float* __restrict__ bfb,
    const float* __restrict__ bgb,
    const float* __restrict__ bhb,
    unsigned short* __restrict__ fKh,
    unsigned short* __restrict__ fKl,
    unsigned short* __restrict__ gQh,
    unsigned short* __restrict__ gQl,
    unsigned short* __restrict__ hT) {
    __shared__ short sm[4 * 64 * 136];   // XH, XL, WH, WL [64][128->136]
    const int XH = 0, XL = 64 * 136, WH = 2 * 64 * 136, WL = 3 * 64 * 136;
    int tid = threadIdx.x;
    int wave = tid >> 6, lane = tid & 63, lq = lane & 15, quad = lane >> 4;
    int rt = blockIdx.x;
    const float* xbase = x + (size_t)rt * 64 * 256;

    f32x4 zero4 = {0.f, 0.f, 0.f, 0.f};
    f32x4 acc[5][4];
#pragma unroll
    for (int cb = 0; cb < 5; ++cb)
#pragma unroll
        for (int ct = 0; ct < 4; ++ct) acc[cb][ct] = zero4;

    for (int ph = 0; ph < 2; ++ph) {
        int k0 = ph * 128;
        __syncthreads();
        // stage x tile (hi+lo), converting fp32 -> bf16 pair
#pragma unroll
        for (int u = 0; u < 4; ++u) {
            int q = u * 256 + tid;
            int row = q >> 4, kc = q & 15;
            const float* src = &xbase[row * 256 + k0 + kc * 8];
            f32x4 a0 = *(const f32x4*)src;
            f32x4 a1 = *(const f32x4*)(src + 4);
            short8 sh, sl;
#pragma unroll
            for (int j = 0; j < 4; ++j) {
                unsigned short h0 = f2bf(a0[j]);
                sh[j] = (short)h0; sl[j] = (short)f2bf(a0[j] - bf2f(h0));
                unsigned short h1 = f2bf(a1[j]);
                sh[4 + j] = (short)h1; sl[4 + j] = (short)f2bf(a1[j] - bf2f(h1));
            }
            *(short8*)&sm[XH + row * 136 + kc * 8] = sh;
            *(short8*)&sm[XL + row * 136 + kc * 8] = sl;
        }
        for (int cb = 0; cb < 5; ++cb) {
            __syncthreads();
            int cstart = (cb < 4) ? (64 + cb * 64) : 0;
#pragma unroll
            for (int u = 0; u < 4; ++u) {
                int q = u * 256 + tid;
                int row = q >> 4, kc = q & 15;
                *(short8*)&sm[WH + row * 136 + kc * 8] =
                    *(const short8*)&wTh[(cstart + row) * 256 + k0 + kc * 8];
            }
            if (cb == 4) {
#pragma unroll
                for (int u = 0; u < 4; ++u) {
                    int q = u * 256 + tid;
                    int row = q >> 4, kc = q & 15;
                    *(short8*)&sm[WL + row * 136 + kc * 8] =
                        *(const short8*)&wTl[row * 256 + k0 + kc * 8];
                }
            }
            __syncthreads();
#pragma unroll
            for (int ks = 0; ks < 4; ++ks) {
                short8 ah = *(const short8*)&sm[XH + (wave * 16 + lq) * 136 + ks * 32 + quad * 8];
                short8 al = *(const short8*)&sm[XL + (wave * 16 + lq) * 136 + ks * 32 + quad * 8];
#pragma unroll
                for (int ct = 0; ct < 4; ++ct) {
                    short8 bh = *(const short8*)&sm[WH + (lq + 16 * ct) * 136 + ks * 32 + quad * 8];
                    acc[cb][ct] = __builtin_amdgcn_mfma_f32_16x16x32_bf16(ah, bh, acc[cb][ct], 0, 0, 0);
                    if (cb == 4) {
                        short8 bl = *(const short8*)&sm[WL + (lq + 16 * ct) * 136 + ks * 32 + quad * 8];
                        acc[cb][ct] = __builtin_amdgcn_mfma_f32_16x16x32_bf16(al, bh, acc[cb][ct], 0, 0, 0);
                        acc[cb][ct] = __builtin_amdgcn_mfma_f32_16x16x32_bf16(ah, bl, acc[cb][ct], 0, 0, 0);
                    }
                }
            }
        }
    }

    int rowl = wave * 16 + quad * 4;
    int grow0 = rt * 64;
    int bidx = grow0 >> 12;

    // ---- h epilogue: fragment-linear short4 stores ----
#pragma unroll
    for (int cb = 0; cb < 4; ++cb) {
        int n0 = (grow0 & 4095) + rowl;
#pragma unroll
        for (int ct = 0; ct < 4; ++ct) {
            int c = cb * 64 + lq + 16 * ct;
            float bias = bhb[c];
            short4_t pk;
#pragma unroll
            for (int r = 0; r < 4; ++r) pk[r] = (short)f2bf(acc[cb][ct][r] + bias);
            size_t a8 = (((size_t)(bidx * 16 + (c >> 4)) * 128 + (n0 >> 5)) * 64 +
                         ((n0 & 31) >> 3) * 16 + (c & 15)) * 8 + (n0 & 7);
            *(short4_t*)&hT[a8] = pk;
        }
    }

    // ---- f,g epilogue: hi/lo pairs, fragment-linear ----
#pragma unroll
    for (int ct = 0; ct < 4; ++ct) {
        int coll = lq + 16 * ct;
#pragma unroll
        for (int r = 0; r < 4; ++r) {
            int grow = grow0 + rowl + r;
            int n = grow & 4095;
            float v = acc[4][ct][r];
            if (coll < 32) {
                size_t o = (size_t)(bidx * 256 + (n >> 4)) * 512 +
                           ((coll >> 3) * 16 + (n & 15)) * 8 + (coll & 7);
                v += bfb[coll];
                unsigned short h = f2bf(v);
                fKh[o] = h;
                fKl[o] = f2bf(v - bf2f(h));
            } else {
                int cg = coll - 32;
                size_t og = (size_t)(bidx * 256 + (n >> 4)) * 512 +
                            ((cg >> 3) * 16 + (n & 15)) * 8 + (cg & 7);
                v += bgb[cg];
                unsigned short h = f2bf(v);
                gQh[og] = h;
                gQl[og] = f2bf(v - bf2f(h));
            }
        }
    }
}

// ---------------- kernel C: flash attention, in-block key-split ------------
// Grid 256 x 512 thr. b = bid&3 (one batch per XCD -> hT slice fits L2),
// qt = bid>>2 (64 q-rows). 8 waves = 2 groups of 4; group g handles keys
// g*2048..+2048 (32 kts). Within a group:
//   S KEY-split: wave w computes keys w*16..+16 for ALL 4 row strips
//     (g frags in regs; f frags wave-exclusive -> DIRECT global loads).
//   PV CHANNEL-split: wave w owns channels w*64..+64 for all 64 rows.
// LDS = P double-buffer only; ONE barrier per kt. No online max (|S|<~40
// << 88 overflow): P = exp(S), l per-lane. Split-k combine IN-BLOCK at end.
#define PSTR 72
__global__ __launch_bounds__(512, 2) void k_attn(
    const unsigned short* __restrict__ fKh,
    const unsigned short* __restrict__ fKl,
    const unsigned short* __restrict__ gQh,
    const unsigned short* __restrict__ gQl,
    const unsigned short* __restrict__ hT,
    const float* __restrict__ x,
    const float* __restrict__ gam_p,
    float* __restrict__ out) {
    __shared__ short Ps[2][2][64 * PSTR];   // [pbuf][group] 36.9 KB
    __shared__ float lsum[8][64];           // 2 KB
    int tid = threadIdx.x;
    int wave = tid >> 6, lane = tid & 63, lq = lane & 15, quad = lane >> 4;
    int grp = wave >> 2, w = wave & 3;
    int b = blockIdx.x & 3, qt = blockIdx.x >> 2;
    int lchunk = quad * 16 + lq;

    const unsigned short* fhB = fKh + (size_t)b * 131072;  // pre-offset: NO b below
    const unsigned short* flB = fKl + (size_t)b * 131072;
    const unsigned short* hB  = hT + (size_t)b * 1048576;

    f32x4 zero4 = {0.f, 0.f, 0.f, 0.f};
    f32x4 acc[16];                          // [rb(4)][ct(4)]
#pragma unroll
    for (int i = 0; i < 16; ++i) acc[i] = zero4;
    float l_part[16];
#pragma unroll
    for (int i = 0; i < 16; ++i) l_part[i] = 0.f;

    // g A-frags for ALL 4 row strips (gQ raw pointer: tile includes b)
    short8 gh[4], gl[4];
#pragma unroll
    for (int rb = 0; rb < 4; ++rb) {
        size_t gt = (size_t)(b * 256 + qt * 4 + rb) * 512 + lchunk * 8;
        gh[rb] = *(const short8*)&gQh[gt];
        gl[rb] = *(const short8*)&gQl[gt];
    }

    int ftbase = grp * 128;    // f tile base (within batch) for this group
    int hkbase = grp * 64;     // 32-key-group base for this group

    for (int kt = 0; kt < 32; ++kt) {
        int p = kt & 1;
        // ---- f frags (wave-exclusive, coalesced 1KB) ----
        int ftile = ftbase + kt * 4 + w;
        short8 fh = *(const short8*)&fhB[(size_t)ftile * 512 + lchunk * 8];
        short8 fl = *(const short8*)&flB[(size_t)ftile * 512 + lchunk * 8];
        // ---- hT B-frags (wave-exclusive channels, coalesced 1KB) ----
        short8 hb[4][2];
#pragma unroll
        for (int ct = 0; ct < 4; ++ct) {
            int ctile = w * 4 + ct;
#pragma unroll
            for (int kk = 0; kk < 2; ++kk) {
                int k32 = hkbase + kt * 2 + kk;
                hb[ct][kk] = *(const short8*)
                    &hB[((size_t)(ctile * 128 + k32) * 64 + lchunk) * 8];
            }
        }

        // ---- S: keys w*16..+16 x all 64 rows (3-term hi/lo) ----
        f32x4 S[4];
#pragma unroll
        for (int rb = 0; rb < 4; ++rb) {
            S[rb] = __builtin_amdgcn_mfma_f32_16x16x32_bf16(gh[rb], fh, zero4, 0, 0, 0);
            S[rb] = __builtin_amdgcn_mfma_f32_16x16x32_bf16(gl[rb], fh, S[rb], 0, 0, 0);
            S[rb] = __builtin_amdgcn_mfma_f32_16x16x32_bf16(gh[rb], fl, S[rb], 0, 0, 0);
        }

        // ---- P = exp(S); per-lane l; P -> LDS ----
#pragma unroll
        for (int rb = 0; rb < 4; ++rb)
#pragma unroll
            for (int r = 0; r < 4; ++r) {
                float e = __expf(S[rb][r]);
                S[rb][r] = e;
                l_part[rb * 4 + r] += e;
            }
#pragma unroll
        for (int rb = 0; rb < 4; ++rb)
#pragma unroll
            for (int r = 0; r < 4; ++r)
                Ps[p][grp][(rb * 16 + quad * 4 + r) * PSTR + w * 16 + lq] =
                    (short)f2bf(S[rb][r]);

        __syncthreads();   // single barrier per kt (P dbuf)

        // ---- PV: all 64 rows x this wave's 64 channels ----
#pragma unroll
        for (int rb = 0; rb < 4; ++rb) {
            short8 pa0 = *(const short8*)&Ps[p][grp][(rb * 16 + lq) * PSTR + quad * 8];
            short8 pa1 = *(const short8*)&Ps[p][grp][(rb * 16 + lq) * PSTR + 32 + quad * 8];
#pragma unroll
            for (int ct = 0; ct < 4; ++ct) {
                acc[rb * 4 + ct] = __builtin_amdgcn_mfma_f32_16x16x32_bf16(pa0, hb[ct][0], acc[rb * 4 + ct], 0, 0, 0);
                acc[rb * 4 + ct] = __builtin_amdgcn_mfma_f32_16x16x32_bf16(pa1, hb[ct][1], acc[rb * 4 + ct], 0, 0, 0);
            }
        }
    }

    // ---- l: reduce over 16 key-lanes, publish per wave ----
#pragma unroll
    for (int i = 0; i < 16; ++i) {
        float s = l_part[i];
        s += __shfl_xor(s, 1);
        s += __shfl_xor(s, 2);
        s += __shfl_xor(s, 4);
        s += __shfl_xor(s, 8);
        l_part[i] = s;
    }
    if (lq == 0) {
#pragma unroll
        for (int rb = 0; rb < 4; ++rb)
#pragma unroll
            for (int r = 0; r < 4; ++r)
                lsum[wave][rb * 16 + quad * 4 + r] = l_part[rb * 4 + r];
    }
    __syncthreads();

    // ---- in-block split-k combine: group 1 -> group 0 via LDS ----
    float* xb = (float*)&Ps[0][0][0];   // 16 KB scratch per strip
    for (int rb = 0; rb < 4; ++rb) {
        if (grp == 1) {
#pragma unroll
            for (int ct = 0; ct < 4; ++ct)
#pragma unroll
                for (int r = 0; r < 4; ++r)
                    xb[(quad * 4 + r) * 256 + w * 64 + ct * 16 + lq] = acc[rb * 4 + ct][r];
        }
        __syncthreads();
        if (grp == 0) {
#pragma unroll
            for (int ct = 0; ct < 4; ++ct)
#pragma unroll
                for (int r = 0; r < 4; ++r)
                    acc[rb * 4 + ct][r] += xb[(quad * 4 + r) * 256 + w * 64 + ct * 16 + lq];
        }
        __syncthreads();
    }

    // ---- group 0 normalizes + residual + store ----
    if (grp == 0) {
        float gam = gam_p[0];
#pragma unroll
        for (int rb = 0; rb < 4; ++rb) {
            float linv[4];
#pragma unroll
            for (int r = 0; r < 4; ++r) {
                int row = rb * 16 + quad * 4 + r;
                float lt = 0.f;
#pragma unroll
                for (int wv = 0; wv < 8; ++wv) lt += lsum[wv][row];
                linv[r] = 1.0f / lt;
            }
#pragma unroll
            for (int ct = 0; ct < 4; ++ct) {
                int c = w * 64 + ct * 16 + lq;
#pragma unroll
                for (int r = 0; r < 4; ++r) {
                    int n = qt * 64 + rb * 16 + quad * 4 + r;
                    size_t idx = ((size_t)(b * 4096 + n)) * 256 + c;
                    out[idx] = gam * (acc[rb * 4 + ct][r] * linv[r]) + x[idx];
                }
            }
        }
    }
}

extern "C" void kernel_launch(void* const* d_in, const int* in_sizes, int n_in,
                              void* d_out, int out_size, void* d_ws, size_t ws_size,
                              hipStream_t stream) {
    const float* x   = (const float*)d_in[0];
    const float* Wf  = (const float*)d_in[1];
    const float* bfb = (const float*)d_in[2];
    const float* Wg  = (const float*)d_in[3];
    const float* bgb = (const float*)d_in[4];
    const float* Wh  = (const float*)d_in[5];
    const float* bhb = (const float*)d_in[6];
    const float* gam = (const float*)d_in[7];
    float* out = (float*)d_out;

    char* ws = (char*)d_ws;
    const size_t MI = 1u << 20;
    unsigned short* fKh = (unsigned short*)(ws);                  // 1 MiB
    unsigned short* fKl = (unsigned short*)(ws + 1 * MI);         // 1 MiB
    unsigned short* gQh = (unsigned short*)(ws + 2 * MI);         // 1 MiB
    unsigned short* gQl = (unsigned short*)(ws + 3 * MI);         // 1 MiB
    unsigned short* hT  = (unsigned short*)(ws + 4 * MI);         // 8 MiB
    unsigned short* wTh = (unsigned short*)(ws + 12 * MI);        // 160 KiB
    unsigned short* wTl = (unsigned short*)(ws + 12 * MI + 160 * 1024); // 32 KiB

    k_wtrans<<<dim3(320), dim3(256), 0, stream>>>(Wf, Wg, Wh, wTh, wTl);
    k_proj<<<dim3(256), dim3(256), 0, stream>>>(x, wTh, wTl, bfb, bgb, bhb,
                                                fKh, fKl, gQh, gQl, hT);
    k_attn<<<dim3(256), dim3(512), 0, stream>>>(fKh, fKl, gQh, gQl, hT,
                                                x, gam, out);
}